// Round 1
// baseline (16484.409 us; speedup 1.0000x reference)
//
#include <hip/hip_runtime.h>
#include <math.h>

#define B_  4
#define L_  512
#define D_  512
#define DIN 1024
#define DST 16
#define DCV 4
#define DTR 32
#define NL  3
#define H2  256

__device__ __forceinline__ float fast_sigmoid(float x) { return 1.f / (1.f + __expf(-x)); }

// C[M,N] = act(A[M,K] @ B[N,K]^T + bias + bias2); ACC: C += ...
// ACT: 0 = none, 1 = softplus
template<int ACT, bool ACC>
__global__ __launch_bounds__(256) void gemm_nt(
    const float* __restrict__ A, const float* __restrict__ Bm, float* __restrict__ C,
    int M, int N, int K, int lda, int ldb, int ldc,
    const float* __restrict__ bias, const float* __restrict__ bias2)
{
  __shared__ __align__(16) float As[16][64];
  __shared__ __align__(16) float Bs[16][64];
  const int tid = threadIdx.x;
  const int tx = tid & 15, ty = tid >> 4;
  const int m0 = blockIdx.y * 64, n0 = blockIdx.x * 64;
  const int r = tid >> 2, kq = (tid & 3) * 4;
  float acc[4][4] = {};
  for (int k0 = 0; k0 < K; k0 += 16) {
    float4 av = *(const float4*)(A  + (size_t)(m0 + r) * lda + (k0 + kq));
    float4 bv = *(const float4*)(Bm + (size_t)(n0 + r) * ldb + (k0 + kq));
    As[kq+0][r] = av.x; As[kq+1][r] = av.y; As[kq+2][r] = av.z; As[kq+3][r] = av.w;
    Bs[kq+0][r] = bv.x; Bs[kq+1][r] = bv.y; Bs[kq+2][r] = bv.z; Bs[kq+3][r] = bv.w;
    __syncthreads();
    #pragma unroll
    for (int kk = 0; kk < 16; ++kk) {
      float4 a = *(const float4*)(&As[kk][ty*4]);
      float4 b = *(const float4*)(&Bs[kk][tx*4]);
      float aa[4] = {a.x, a.y, a.z, a.w};
      float bb[4] = {b.x, b.y, b.z, b.w};
      #pragma unroll
      for (int i = 0; i < 4; ++i)
        #pragma unroll
        for (int j = 0; j < 4; ++j)
          acc[i][j] = fmaf(aa[i], bb[j], acc[i][j]);
    }
    __syncthreads();
  }
  #pragma unroll
  for (int i = 0; i < 4; ++i) {
    int m = m0 + ty*4 + i;
    float* cp = C + (size_t)m * ldc + n0 + tx*4;
    #pragma unroll
    for (int j = 0; j < 4; ++j) {
      int n = n0 + tx*4 + j;
      float v = acc[i][j];
      if (bias)  v += bias[n];
      if (bias2) v += bias2[n];
      if (ACT == 1) v = (v > 20.f) ? v : log1pf(__expf(v));
      if (ACC) cp[j] += v; else cp[j] = v;
    }
  }
}

// u[b,l,c] = silu(cb[c] + sum_k xin[b,l-3+k,c] * cw[c,k]), xin = xz[:, :, :1024]
__global__ __launch_bounds__(256) void conv_silu(
    const float* __restrict__ xz, const float* __restrict__ cw, const float* __restrict__ cb,
    float* __restrict__ u)
{
  int t = blockIdx.x * 256 + threadIdx.x;   // over B*L*DIN
  int c  = t & (DIN - 1);
  int bl = t >> 10;
  int l  = bl & (L_ - 1);
  float acc = cb[c];
  #pragma unroll
  for (int k = 0; k < DCV; ++k) {
    int ls = l + k - (DCV - 1);
    if (ls >= 0)
      acc = fmaf(xz[(size_t)(bl + k - (DCV - 1)) * 2048 + c], cw[c * DCV + k], acc);
  }
  u[t] = acc * fast_sigmoid(acc);
}

// selective scan: one thread per (b, c, n); n in low 4 bits of lane -> shfl_xor reduce
__global__ __launch_bounds__(256) void scan_kernel(
    const float* __restrict__ dt, const float* __restrict__ u,
    const float* __restrict__ xdbl, const float* __restrict__ xz,
    const float* __restrict__ A_log, const float* __restrict__ Dp,
    float* __restrict__ y)
{
  int t = blockIdx.x * 256 + threadIdx.x;   // [0, B*DIN*DST)
  int n  = t & 15;
  int bc = t >> 4;
  int c  = bc & (DIN - 1);
  int b  = bc >> 10;
  float Ac = -__expf(A_log[c * DST + n]);
  float Dc = Dp[c];
  float h = 0.f;
  for (int l = 0; l < L_; ++l) {
    size_t base = (size_t)(b * L_ + l);
    float dtv = dt[base * DIN + c];
    float uv  = u [base * DIN + c];
    float Bn  = xdbl[base * 64 + 32 + n];
    float Cn  = xdbl[base * 64 + 48 + n];
    float dA  = __expf(dtv * Ac);
    float du  = dtv * uv;
    h = fmaf(dA, h, du * Bn);
    float p = h * Cn;
    p += __shfl_xor(p, 1, 64);
    p += __shfl_xor(p, 2, 64);
    p += __shfl_xor(p, 4, 64);
    p += __shfl_xor(p, 8, 64);
    if (n == 0) {
      float zv = xz[base * 2048 + 1024 + c];
      float yv = p + uv * Dc;
      yv *= zv * fast_sigmoid(zv);
      y[base * DIN + c] = yv;
    }
  }
}

// m_out[row] = layernorm(a[row] + mo[row]) * g + b   (row length 512, one wave per row)
__global__ __launch_bounds__(64) void resid_ln(
    const float* __restrict__ a, const float* __restrict__ mo,
    const float* __restrict__ g, const float* __restrict__ bta,
    float* __restrict__ outm)
{
  int row = blockIdx.x;
  int lane = threadIdx.x;
  const float* pa = a  + (size_t)row * 512;
  const float* pb = mo + (size_t)row * 512;
  float v[8];
  float s = 0.f, s2 = 0.f;
  #pragma unroll
  for (int i = 0; i < 8; ++i) {
    float x = pa[lane + i * 64] + pb[lane + i * 64];
    v[i] = x; s += x; s2 += x * x;
  }
  #pragma unroll
  for (int off = 1; off < 64; off <<= 1) {
    s  += __shfl_xor(s,  off, 64);
    s2 += __shfl_xor(s2, off, 64);
  }
  float mean = s * (1.f / 512.f);
  float var  = s2 * (1.f / 512.f) - mean * mean;
  float rstd = rsqrtf(var + 1e-5f);
  #pragma unroll
  for (int i = 0; i < 8; ++i) {
    int cidx = lane + i * 64;
    outm[(size_t)row * 512 + cidx] = (v[i] - mean) * rstd * g[cidx] + bta[cidx];
  }
}

// LSTM recurrence: one block per (dir, b); gx = x@wih^T + bih + bhh precomputed,
// laid out [b*L + l][dir*1024 + j]
__global__ __launch_bounds__(1024) void lstm_rec(
    const float* __restrict__ gx, const float* __restrict__ whh,
    float* __restrict__ outf, float* __restrict__ outb)
{
  int dir = blockIdx.x >> 2;
  int b   = blockIdx.x & 3;
  int j   = threadIdx.x;
  __shared__ __align__(16) float h_s[H2];
  __shared__ __align__(16) float g_s[4 * H2];
  if (j < H2) h_s[j] = 0.f;
  float c_reg = 0.f;
  const float* wrow = whh + ((size_t)dir * 1024 + j) * H2;
  float* outp = dir ? outb : outf;
  __syncthreads();
  for (int s = 0; s < L_; ++s) {
    int l = dir ? (L_ - 1 - s) : s;
    float acc = gx[(size_t)(b * L_ + l) * 2048 + dir * 1024 + j];
    #pragma unroll 8
    for (int k = 0; k < H2; k += 4) {
      float4 w4 = *(const float4*)(wrow + k);
      float4 h4 = *(const float4*)(h_s + k);
      acc = fmaf(w4.x, h4.x, acc);
      acc = fmaf(w4.y, h4.y, acc);
      acc = fmaf(w4.z, h4.z, acc);
      acc = fmaf(w4.w, h4.w, acc);
    }
    g_s[j] = acc;
    __syncthreads();
    if (j < H2) {
      float gi = g_s[j], gf = g_s[j + 256], gg = g_s[j + 512], go = g_s[j + 768];
      float si = fast_sigmoid(gi);
      float sf = fast_sigmoid(gf);
      float so = fast_sigmoid(go);
      float tg = tanhf(gg);
      c_reg = sf * c_reg + si * tg;
      float hv = so * tanhf(c_reg);
      h_s[j] = hv;
      outp[(size_t)(b * L_ + l) * H2 + j] = hv;
    }
    __syncthreads();
  }
}

extern "C" void kernel_launch(void* const* d_in, const int* in_sizes, int n_in,
                              void* d_out, int out_size, void* d_ws, size_t ws_size,
                              hipStream_t stream)
{
  const float* x    = (const float*)d_in[0];
  const float* wi   = (const float*)d_in[1];
  const float* cw   = (const float*)d_in[2];
  const float* cb   = (const float*)d_in[3];
  const float* xpw  = (const float*)d_in[4];
  const float* dw   = (const float*)d_in[5];
  const float* db   = (const float*)d_in[6];
  const float* Alog = (const float*)d_in[7];
  const float* Dp   = (const float*)d_in[8];
  const float* wo   = (const float*)d_in[9];
  const float* lng  = (const float*)d_in[10];
  const float* lnb  = (const float*)d_in[11];
  const float* wih  = (const float*)d_in[12];
  const float* whh  = (const float*)d_in[13];
  const float* bih  = (const float*)d_in[14];
  const float* bhh  = (const float*)d_in[15];
  const float* fw   = (const float*)d_in[16];
  const float* fb   = (const float*)d_in[17];
  float* out = (float*)d_out;

  float* F    = (float*)d_ws;
  float* xz   = F;                 // 4,194,304 floats (B*L*2048); aliased with gx
  float* gx   = F;                 // LSTM gate precompute, consumed before mamba chain
  float* u    = F + 4194304;       // 2,097,152
  float* xdbl = F + 6291456;       //   131,072
  float* dt   = F + 6422528;       // 2,097,152
  float* ybuf = F + 8519680;       // 2,097,152
  float* mo   = F + 10616832;      // 1,048,576
  float* mbuf = F + 11665408;      // 1,048,576
  float* lf   = F + 12713984;      //   524,288
  float* lb   = F + 13238272;      //   524,288

  const int M = B_ * L_;           // 2048
  dim3 blk(256);

  // LSTM input projection for both dirs + both biases in one GEMM:
  // gx[(b,l)][dir*1024 + j] = x @ wih_all^T + bih + bhh
  gemm_nt<0,false><<<dim3(2048/64, M/64), blk, 0, stream>>>(
      x, wih, gx, M, 2048, 512, 512, 512, 2048, bih, bhh);
  lstm_rec<<<dim3(8), dim3(1024), 0, stream>>>(gx, whh, lf, lb);

  for (int i = 0; i < NL; ++i) {
    const float* min = (i == 0) ? x : mbuf;
    // xz = m @ in_proj_w^T
    gemm_nt<0,false><<<dim3(2048/64, M/64), blk, 0, stream>>>(
        min, wi + (size_t)i*2048*512, xz, M, 2048, 512, 512, 512, 2048, nullptr, nullptr);
    // u = silu(causal depthwise conv(xin) + cb)
    conv_silu<<<dim3((M*DIN)/256), blk, 0, stream>>>(
        xz, cw + (size_t)i*DIN*DCV, cb + i*DIN, u);
    // xdbl = u @ x_proj_w^T
    gemm_nt<0,false><<<dim3(1, M/64), blk, 0, stream>>>(
        u, xpw + (size_t)i*64*1024, xdbl, M, 64, 1024, 1024, 1024, 64, nullptr, nullptr);
    // dt = softplus(dt_in @ dt_proj_w^T + db)
    gemm_nt<1,false><<<dim3(1024/64, M/64), blk, 0, stream>>>(
        xdbl, dw + (size_t)i*1024*32, dt, M, 1024, 32, 64, 32, 1024, db + i*1024, nullptr);
    // selective scan + D skip + gate by silu(z)
    scan_kernel<<<dim3((B_*DIN*DST)/256), blk, 0, stream>>>(
        dt, u, xdbl, xz, Alog + (size_t)i*DIN*DST, Dp + i*DIN, ybuf);
    // mo = y @ out_proj_w^T
    gemm_nt<0,false><<<dim3(512/64, M/64), blk, 0, stream>>>(
        ybuf, wo + (size_t)i*512*1024, mo, M, 512, 1024, 1024, 1024, 512, nullptr, nullptr);
    // m = layernorm(m + mo)
    resid_ln<<<dim3(M), dim3(64), 0, stream>>>(
        min, mo, lng + i*512, lnb + i*512, mbuf);
  }

  // fusion: out = [m | lf | lb] @ fusion_w^T + fb, as 3 K-split GEMM passes
  gemm_nt<0,false><<<dim3(512/64, M/64), blk, 0, stream>>>(
      mbuf, fw,       out, M, 512, 512, 512, 1024, 512, fb, nullptr);
  gemm_nt<0,true><<<dim3(512/64, M/64), blk, 0, stream>>>(
      lf,   fw + 512, out, M, 512, 256, 256, 1024, 512, nullptr, nullptr);
  gemm_nt<0,true><<<dim3(512/64, M/64), blk, 0, stream>>>(
      lb,   fw + 768, out, M, 512, 256, 256, 1024, 512, nullptr, nullptr);
}

// Round 2
// 12359.126 us; speedup vs baseline: 1.3338x; 1.3338x over previous
//
#include <hip/hip_runtime.h>
#include <math.h>

#define B_  4
#define L_  512
#define D_  512
#define DIN 1024
#define DST 16
#define DCV 4
#define DTR 32
#define NL  3
#define H2  256

__device__ __forceinline__ float fast_sigmoid(float x) { return 1.f / (1.f + __expf(-x)); }
__device__ __forceinline__ float fast_tanh(float x) { return 2.f / (1.f + __expf(-2.f * x)) - 1.f; }

// C[M,N] = act(A[M,K] @ B[N,K]^T + bias + bias2); ACC: C += ...
// ACT: 0 = none, 1 = softplus
template<int ACT, bool ACC>
__global__ __launch_bounds__(256) void gemm_nt(
    const float* __restrict__ A, const float* __restrict__ Bm, float* __restrict__ C,
    int M, int N, int K, int lda, int ldb, int ldc,
    const float* __restrict__ bias, const float* __restrict__ bias2)
{
  __shared__ __align__(16) float As[16][64];
  __shared__ __align__(16) float Bs[16][64];
  const int tid = threadIdx.x;
  const int tx = tid & 15, ty = tid >> 4;
  const int m0 = blockIdx.y * 64, n0 = blockIdx.x * 64;
  const int r = tid >> 2, kq = (tid & 3) * 4;
  float acc[4][4] = {};
  for (int k0 = 0; k0 < K; k0 += 16) {
    float4 av = *(const float4*)(A  + (size_t)(m0 + r) * lda + (k0 + kq));
    float4 bv = *(const float4*)(Bm + (size_t)(n0 + r) * ldb + (k0 + kq));
    As[kq+0][r] = av.x; As[kq+1][r] = av.y; As[kq+2][r] = av.z; As[kq+3][r] = av.w;
    Bs[kq+0][r] = bv.x; Bs[kq+1][r] = bv.y; Bs[kq+2][r] = bv.z; Bs[kq+3][r] = bv.w;
    __syncthreads();
    #pragma unroll
    for (int kk = 0; kk < 16; ++kk) {
      float4 a = *(const float4*)(&As[kk][ty*4]);
      float4 b = *(const float4*)(&Bs[kk][tx*4]);
      float aa[4] = {a.x, a.y, a.z, a.w};
      float bb[4] = {b.x, b.y, b.z, b.w};
      #pragma unroll
      for (int i = 0; i < 4; ++i)
        #pragma unroll
        for (int j = 0; j < 4; ++j)
          acc[i][j] = fmaf(aa[i], bb[j], acc[i][j]);
    }
    __syncthreads();
  }
  #pragma unroll
  for (int i = 0; i < 4; ++i) {
    int m = m0 + ty*4 + i;
    float* cp = C + (size_t)m * ldc + n0 + tx*4;
    #pragma unroll
    for (int j = 0; j < 4; ++j) {
      int n = n0 + tx*4 + j;
      float v = acc[i][j];
      if (bias)  v += bias[n];
      if (bias2) v += bias2[n];
      if (ACT == 1) v = (v > 20.f) ? v : log1pf(__expf(v));
      if (ACC) cp[j] += v; else cp[j] = v;
    }
  }
}

// u[b,l,c] = silu(cb[c] + sum_k xin[b,l-3+k,c] * cw[c,k]), xin = xz[:, :, :1024]
__global__ __launch_bounds__(256) void conv_silu(
    const float* __restrict__ xz, const float* __restrict__ cw, const float* __restrict__ cb,
    float* __restrict__ u)
{
  int t = blockIdx.x * 256 + threadIdx.x;   // over B*L*DIN
  int c  = t & (DIN - 1);
  int bl = t >> 10;
  int l  = bl & (L_ - 1);
  float acc = cb[c];
  #pragma unroll
  for (int k = 0; k < DCV; ++k) {
    int ls = l + k - (DCV - 1);
    if (ls >= 0)
      acc = fmaf(xz[(size_t)(bl + k - (DCV - 1)) * 2048 + c], cw[c * DCV + k], acc);
  }
  u[t] = acc * fast_sigmoid(acc);
}

// selective scan: one thread per (b, c, n); n in low 4 bits of lane -> shfl_xor reduce
__global__ __launch_bounds__(256) void scan_kernel(
    const float* __restrict__ dt, const float* __restrict__ u,
    const float* __restrict__ xdbl, const float* __restrict__ xz,
    const float* __restrict__ A_log, const float* __restrict__ Dp,
    float* __restrict__ y)
{
  int t = blockIdx.x * 256 + threadIdx.x;   // [0, B*DIN*DST)
  int n  = t & 15;
  int bc = t >> 4;
  int c  = bc & (DIN - 1);
  int b  = bc >> 10;
  float Ac = -__expf(A_log[c * DST + n]);
  float Dc = Dp[c];
  float h = 0.f;
  for (int l = 0; l < L_; ++l) {
    size_t base = (size_t)(b * L_ + l);
    float dtv = dt[base * DIN + c];
    float uv  = u [base * DIN + c];
    float Bn  = xdbl[base * 64 + 32 + n];
    float Cn  = xdbl[base * 64 + 48 + n];
    float dA  = __expf(dtv * Ac);
    float du  = dtv * uv;
    h = fmaf(dA, h, du * Bn);
    float p = h * Cn;
    p += __shfl_xor(p, 1, 64);
    p += __shfl_xor(p, 2, 64);
    p += __shfl_xor(p, 4, 64);
    p += __shfl_xor(p, 8, 64);
    if (n == 0) {
      float zv = xz[base * 2048 + 1024 + c];
      float yv = p + uv * Dc;
      yv *= zv * fast_sigmoid(zv);
      y[base * DIN + c] = yv;
    }
  }
}

// m_out[row] = layernorm(a[row] + mo[row]) * g + b   (row length 512, one wave per row)
__global__ __launch_bounds__(64) void resid_ln(
    const float* __restrict__ a, const float* __restrict__ mo,
    const float* __restrict__ g, const float* __restrict__ bta,
    float* __restrict__ outm)
{
  int row = blockIdx.x;
  int lane = threadIdx.x;
  const float* pa = a  + (size_t)row * 512;
  const float* pb = mo + (size_t)row * 512;
  float v[8];
  float s = 0.f, s2 = 0.f;
  #pragma unroll
  for (int i = 0; i < 8; ++i) {
    float x = pa[lane + i * 64] + pb[lane + i * 64];
    v[i] = x; s += x; s2 += x * x;
  }
  #pragma unroll
  for (int off = 1; off < 64; off <<= 1) {
    s  += __shfl_xor(s,  off, 64);
    s2 += __shfl_xor(s2, off, 64);
  }
  float mean = s * (1.f / 512.f);
  float var  = s2 * (1.f / 512.f) - mean * mean;
  float rstd = rsqrtf(var + 1e-5f);
  #pragma unroll
  for (int i = 0; i < 8; ++i) {
    int cidx = lane + i * 64;
    outm[(size_t)row * 512 + cidx] = (v[i] - mean) * rstd * g[cidx] + bta[cidx];
  }
}

// LSTM recurrence: one block per (dir, b). Weight row for output j (256 floats)
// lives in registers (64 float4 = 256 VGPR); h broadcast via LDS.
// gx = x@wih_all^T + bih + bhh, laid out [b*L + l][dir*1024 + j]
__global__ __launch_bounds__(1024, 4) void lstm_rec(
    const float* __restrict__ gx, const float* __restrict__ whh,
    float* __restrict__ outf, float* __restrict__ outb)
{
  int dir = blockIdx.x >> 2;
  int b   = blockIdx.x & 3;
  int j   = threadIdx.x;
  __shared__ __align__(16) float h_s[H2];
  __shared__ __align__(16) float g_s[4 * H2];

  // one-time: pull this output's weight row into registers
  const float4* wrow = (const float4*)(whh + ((size_t)dir * 1024 + j) * H2);
  float4 w[64];
  #pragma unroll
  for (int k = 0; k < 64; ++k) w[k] = wrow[k];

  if (j < H2) h_s[j] = 0.f;
  float c_reg = 0.f;
  float* outp = dir ? outb : outf;
  __syncthreads();

  for (int s = 0; s < L_; ++s) {
    int l = dir ? (L_ - 1 - s) : s;
    float a0 = gx[(size_t)(b * L_ + l) * 2048 + dir * 1024 + j];
    float a1 = 0.f, a2 = 0.f, a3 = 0.f;
    #pragma unroll
    for (int k = 0; k < 64; k += 4) {
      float4 h0 = *(const float4*)(h_s + 4*k);
      float4 h1 = *(const float4*)(h_s + 4*k + 4);
      float4 h2 = *(const float4*)(h_s + 4*k + 8);
      float4 h3 = *(const float4*)(h_s + 4*k + 12);
      a0 = fmaf(w[k  ].x, h0.x, a0); a0 = fmaf(w[k  ].y, h0.y, a0);
      a0 = fmaf(w[k  ].z, h0.z, a0); a0 = fmaf(w[k  ].w, h0.w, a0);
      a1 = fmaf(w[k+1].x, h1.x, a1); a1 = fmaf(w[k+1].y, h1.y, a1);
      a1 = fmaf(w[k+1].z, h1.z, a1); a1 = fmaf(w[k+1].w, h1.w, a1);
      a2 = fmaf(w[k+2].x, h2.x, a2); a2 = fmaf(w[k+2].y, h2.y, a2);
      a2 = fmaf(w[k+2].z, h2.z, a2); a2 = fmaf(w[k+2].w, h2.w, a2);
      a3 = fmaf(w[k+3].x, h3.x, a3); a3 = fmaf(w[k+3].y, h3.y, a3);
      a3 = fmaf(w[k+3].z, h3.z, a3); a3 = fmaf(w[k+3].w, h3.w, a3);
    }
    g_s[j] = (a0 + a1) + (a2 + a3);
    __syncthreads();
    if (j < H2) {
      float gi = g_s[j], gf = g_s[j + 256], gg = g_s[j + 512], go = g_s[j + 768];
      float si = fast_sigmoid(gi);
      float sf = fast_sigmoid(gf);
      float so = fast_sigmoid(go);
      float tg = fast_tanh(gg);
      c_reg = sf * c_reg + si * tg;
      float hv = so * fast_tanh(c_reg);
      h_s[j] = hv;
      outp[(size_t)(b * L_ + l) * H2 + j] = hv;
    }
    __syncthreads();
  }
}

extern "C" void kernel_launch(void* const* d_in, const int* in_sizes, int n_in,
                              void* d_out, int out_size, void* d_ws, size_t ws_size,
                              hipStream_t stream)
{
  const float* x    = (const float*)d_in[0];
  const float* wi   = (const float*)d_in[1];
  const float* cw   = (const float*)d_in[2];
  const float* cb   = (const float*)d_in[3];
  const float* xpw  = (const float*)d_in[4];
  const float* dw   = (const float*)d_in[5];
  const float* db   = (const float*)d_in[6];
  const float* Alog = (const float*)d_in[7];
  const float* Dp   = (const float*)d_in[8];
  const float* wo   = (const float*)d_in[9];
  const float* lng  = (const float*)d_in[10];
  const float* lnb  = (const float*)d_in[11];
  const float* wih  = (const float*)d_in[12];
  const float* whh  = (const float*)d_in[13];
  const float* bih  = (const float*)d_in[14];
  const float* bhh  = (const float*)d_in[15];
  const float* fw   = (const float*)d_in[16];
  const float* fb   = (const float*)d_in[17];
  float* out = (float*)d_out;

  float* F    = (float*)d_ws;
  float* xz   = F;                 // 4,194,304 floats (B*L*2048); aliased with gx
  float* gx   = F;                 // LSTM gate precompute, consumed before mamba chain
  float* u    = F + 4194304;       // 2,097,152
  float* xdbl = F + 6291456;       //   131,072
  float* dt   = F + 6422528;       // 2,097,152
  float* ybuf = F + 8519680;       // 2,097,152
  float* mo   = F + 10616832;      // 1,048,576
  float* mbuf = F + 11665408;      // 1,048,576
  float* lf   = F + 12713984;      //   524,288
  float* lb   = F + 13238272;      //   524,288

  const int M = B_ * L_;           // 2048
  dim3 blk(256);

  // LSTM input projection for both dirs + both biases in one GEMM:
  // gx[(b,l)][dir*1024 + j] = x @ wih_all^T + bih + bhh
  gemm_nt<0,false><<<dim3(2048/64, M/64), blk, 0, stream>>>(
      x, wih, gx, M, 2048, 512, 512, 512, 2048, bih, bhh);
  lstm_rec<<<dim3(8), dim3(1024), 0, stream>>>(gx, whh, lf, lb);

  for (int i = 0; i < NL; ++i) {
    const float* min = (i == 0) ? x : mbuf;
    // xz = m @ in_proj_w^T
    gemm_nt<0,false><<<dim3(2048/64, M/64), blk, 0, stream>>>(
        min, wi + (size_t)i*2048*512, xz, M, 2048, 512, 512, 512, 2048, nullptr, nullptr);
    // u = silu(causal depthwise conv(xin) + cb)
    conv_silu<<<dim3((M*DIN)/256), blk, 0, stream>>>(
        xz, cw + (size_t)i*DIN*DCV, cb + i*DIN, u);
    // xdbl = u @ x_proj_w^T
    gemm_nt<0,false><<<dim3(1, M/64), blk, 0, stream>>>(
        u, xpw + (size_t)i*64*1024, xdbl, M, 64, 1024, 1024, 1024, 64, nullptr, nullptr);
    // dt = softplus(dt_in @ dt_proj_w^T + db)
    gemm_nt<1,false><<<dim3(1024/64, M/64), blk, 0, stream>>>(
        xdbl, dw + (size_t)i*1024*32, dt, M, 1024, 32, 64, 32, 1024, db + i*1024, nullptr);
    // selective scan + D skip + gate by silu(z)
    scan_kernel<<<dim3((B_*DIN*DST)/256), blk, 0, stream>>>(
        dt, u, xdbl, xz, Alog + (size_t)i*DIN*DST, Dp + i*DIN, ybuf);
    // mo = y @ out_proj_w^T
    gemm_nt<0,false><<<dim3(512/64, M/64), blk, 0, stream>>>(
        ybuf, wo + (size_t)i*512*1024, mo, M, 512, 1024, 1024, 1024, 512, nullptr, nullptr);
    // m = layernorm(m + mo)
    resid_ln<<<dim3(M), dim3(64), 0, stream>>>(
        min, mo, lng + i*512, lnb + i*512, mbuf);
  }

  // fusion: out = [m | lf | lb] @ fusion_w^T + fb, as 3 K-split GEMM passes
  gemm_nt<0,false><<<dim3(512/64, M/64), blk, 0, stream>>>(
      mbuf, fw,       out, M, 512, 512, 512, 1024, 512, fb, nullptr);
  gemm_nt<0,true><<<dim3(512/64, M/64), blk, 0, stream>>>(
      lf,   fw + 512, out, M, 512, 256, 256, 1024, 512, nullptr, nullptr);
  gemm_nt<0,true><<<dim3(512/64, M/64), blk, 0, stream>>>(
      lb,   fw + 768, out, M, 512, 256, 256, 1024, 512, nullptr, nullptr);
}

// Round 3
// 2977.264 us; speedup vs baseline: 5.5368x; 4.1512x over previous
//
#include <hip/hip_runtime.h>
#include <math.h>

#define B_  4
#define L_  512
#define D_  512
#define DIN 1024
#define DST 16
#define DCV 4
#define DTR 32
#define NL  3
#define H2  256

typedef _Float16 __f16;
typedef __f16 f16x2 __attribute__((ext_vector_type(2)));

__device__ __forceinline__ float fast_sigmoid(float x) { return 1.f / (1.f + __expf(-x)); }
__device__ __forceinline__ float fast_tanh(float x) { return 2.f / (1.f + __expf(-2.f * x)) - 1.f; }

__device__ __forceinline__ float dot2f(unsigned a, unsigned b, float c) {
  return __builtin_amdgcn_fdot2(__builtin_bit_cast(f16x2, a),
                                __builtin_bit_cast(f16x2, b), c, false);
}
__device__ __forceinline__ unsigned packf16(float a, float b) {
  f16x2 p; p.x = (__f16)a; p.y = (__f16)b;
  return __builtin_bit_cast(unsigned, p);
}

// C[M,N] = act(A[M,K] @ B[N,K]^T + bias + bias2); ACC: C += ...
// ACT: 0 = none, 1 = softplus
template<int ACT, bool ACC>
__global__ __launch_bounds__(256) void gemm_nt(
    const float* __restrict__ A, const float* __restrict__ Bm, float* __restrict__ C,
    int M, int N, int K, int lda, int ldb, int ldc,
    const float* __restrict__ bias, const float* __restrict__ bias2)
{
  __shared__ __align__(16) float As[16][64];
  __shared__ __align__(16) float Bs[16][64];
  const int tid = threadIdx.x;
  const int tx = tid & 15, ty = tid >> 4;
  const int m0 = blockIdx.y * 64, n0 = blockIdx.x * 64;
  const int r = tid >> 2, kq = (tid & 3) * 4;
  float acc[4][4] = {};
  for (int k0 = 0; k0 < K; k0 += 16) {
    float4 av = *(const float4*)(A  + (size_t)(m0 + r) * lda + (k0 + kq));
    float4 bv = *(const float4*)(Bm + (size_t)(n0 + r) * ldb + (k0 + kq));
    As[kq+0][r] = av.x; As[kq+1][r] = av.y; As[kq+2][r] = av.z; As[kq+3][r] = av.w;
    Bs[kq+0][r] = bv.x; Bs[kq+1][r] = bv.y; Bs[kq+2][r] = bv.z; Bs[kq+3][r] = bv.w;
    __syncthreads();
    #pragma unroll
    for (int kk = 0; kk < 16; ++kk) {
      float4 a = *(const float4*)(&As[kk][ty*4]);
      float4 b = *(const float4*)(&Bs[kk][tx*4]);
      float aa[4] = {a.x, a.y, a.z, a.w};
      float bb[4] = {b.x, b.y, b.z, b.w};
      #pragma unroll
      for (int i = 0; i < 4; ++i)
        #pragma unroll
        for (int j = 0; j < 4; ++j)
          acc[i][j] = fmaf(aa[i], bb[j], acc[i][j]);
    }
    __syncthreads();
  }
  #pragma unroll
  for (int i = 0; i < 4; ++i) {
    int m = m0 + ty*4 + i;
    float* cp = C + (size_t)m * ldc + n0 + tx*4;
    #pragma unroll
    for (int j = 0; j < 4; ++j) {
      int n = n0 + tx*4 + j;
      float v = acc[i][j];
      if (bias)  v += bias[n];
      if (bias2) v += bias2[n];
      if (ACT == 1) v = (v > 20.f) ? v : log1pf(__expf(v));
      if (ACC) cp[j] += v; else cp[j] = v;
    }
  }
}

// u[b,l,c] = silu(cb[c] + sum_k xin[b,l-3+k,c] * cw[c,k]), xin = xz[:, :, :1024]
__global__ __launch_bounds__(256) void conv_silu(
    const float* __restrict__ xz, const float* __restrict__ cw, const float* __restrict__ cb,
    float* __restrict__ u)
{
  int t = blockIdx.x * 256 + threadIdx.x;   // over B*L*DIN
  int c  = t & (DIN - 1);
  int bl = t >> 10;
  int l  = bl & (L_ - 1);
  float acc = cb[c];
  #pragma unroll
  for (int k = 0; k < DCV; ++k) {
    int ls = l + k - (DCV - 1);
    if (ls >= 0)
      acc = fmaf(xz[(size_t)(bl + k - (DCV - 1)) * 2048 + c], cw[c * DCV + k], acc);
  }
  u[t] = acc * fast_sigmoid(acc);
}

// selective scan: one thread per (b, c, n); n in low 4 bits of lane -> shfl_xor reduce
__global__ __launch_bounds__(256) void scan_kernel(
    const float* __restrict__ dt, const float* __restrict__ u,
    const float* __restrict__ xdbl, const float* __restrict__ xz,
    const float* __restrict__ A_log, const float* __restrict__ Dp,
    float* __restrict__ y)
{
  int t = blockIdx.x * 256 + threadIdx.x;   // [0, B*DIN*DST)
  int n  = t & 15;
  int bc = t >> 4;
  int c  = bc & (DIN - 1);
  int b  = bc >> 10;
  float Ac = -__expf(A_log[c * DST + n]);
  float Dc = Dp[c];
  float h = 0.f;
  for (int l = 0; l < L_; ++l) {
    size_t base = (size_t)(b * L_ + l);
    float dtv = dt[base * DIN + c];
    float uv  = u [base * DIN + c];
    float Bn  = xdbl[base * 64 + 32 + n];
    float Cn  = xdbl[base * 64 + 48 + n];
    float dA  = __expf(dtv * Ac);
    float du  = dtv * uv;
    h = fmaf(dA, h, du * Bn);
    float p = h * Cn;
    p += __shfl_xor(p, 1, 64);
    p += __shfl_xor(p, 2, 64);
    p += __shfl_xor(p, 4, 64);
    p += __shfl_xor(p, 8, 64);
    if (n == 0) {
      float zv = xz[base * 2048 + 1024 + c];
      float yv = p + uv * Dc;
      yv *= zv * fast_sigmoid(zv);
      y[base * DIN + c] = yv;
    }
  }
}

// m_out[row] = layernorm(a[row] + mo[row]) * g + b   (row length 512, one wave per row)
__global__ __launch_bounds__(64) void resid_ln(
    const float* __restrict__ a, const float* __restrict__ mo,
    const float* __restrict__ g, const float* __restrict__ bta,
    float* __restrict__ outm)
{
  int row = blockIdx.x;
  int lane = threadIdx.x;
  const float* pa = a  + (size_t)row * 512;
  const float* pb = mo + (size_t)row * 512;
  float v[8];
  float s = 0.f, s2 = 0.f;
  #pragma unroll
  for (int i = 0; i < 8; ++i) {
    float x = pa[lane + i * 64] + pb[lane + i * 64];
    v[i] = x; s += x; s2 += x * x;
  }
  #pragma unroll
  for (int off = 1; off < 64; off <<= 1) {
    s  += __shfl_xor(s,  off, 64);
    s2 += __shfl_xor(s2, off, 64);
  }
  float mean = s * (1.f / 512.f);
  float var  = s2 * (1.f / 512.f) - mean * mean;
  float rstd = rsqrtf(var + 1e-5f);
  #pragma unroll
  for (int i = 0; i < 8; ++i) {
    int cidx = lane + i * 64;
    outm[(size_t)row * 512 + cidx] = (v[i] - mean) * rstd * g[cidx] + bta[cidx];
  }
}

// LSTM recurrence. Block per (dir,b), 1024 threads = (unit j in [0,256)) x (k-slice ks in [0,4)).
// Weights f16-packed: gates i,f,g in VGPR (96 dwords/thread), gate o in LDS (128KB).
// h kept packed-f16 in LDS, double-buffered; 4-lane shfl butterfly completes each dot.
// 1 barrier per step.
__global__ __launch_bounds__(1024) void lstm_rec(
    const float* __restrict__ gx, const float* __restrict__ whh,
    float* __restrict__ outf, float* __restrict__ outb)
{
  __shared__ uint4 w_lds[8 * 1024];                 // 128KB o-gate weights
  __shared__ __align__(16) unsigned h_pack[2][144]; // 2 x (4 groups x 36 dwords)
  const int dir = blockIdx.x >> 2, b = blockIdx.x & 3;
  const int t = threadIdx.x;
  const int j = t >> 2, ks = t & 3;
  const size_t wbase = (size_t)dir * 1024 * 256;
  const unsigned wswz = (unsigned)((t * 16) ^ (((t >> 3) & 3) << 4));

  // ---- one-time: load + f16-pack weights ----
  unsigned w0[32], w1[32], w2[32];
#define LOADW(warr, grow)                                                     \
  { const float* wr = whh + wbase + (size_t)((grow) * 256 + j) * 256 + ks*64; \
    _Pragma("unroll")                                                         \
    for (int q = 0; q < 16; ++q) {                                            \
      float4 f = ((const float4*)wr)[q];                                      \
      warr[q*2]   = packf16(f.x, f.y);                                        \
      warr[q*2+1] = packf16(f.z, f.w);                                        \
    } }
  LOADW(w0, 0)
  LOADW(w1, 1)
  LOADW(w2, 2)
#undef LOADW
  {
    const float* wr = whh + wbase + (size_t)(768 + j) * 256 + ks * 64;
    #pragma unroll
    for (int q = 0; q < 8; ++q) {
      float4 fa = ((const float4*)wr)[q*2];
      float4 fb = ((const float4*)wr)[q*2+1];
      uint4 pk;
      pk.x = packf16(fa.x, fa.y); pk.y = packf16(fa.z, fa.w);
      pk.z = packf16(fb.x, fb.y); pk.w = packf16(fb.z, fb.w);
      *(uint4*)((char*)w_lds + (q * 16384 + wswz)) = pk;
    }
  }
  if (t < 288) ((unsigned*)h_pack)[t] = 0u;
  float c_reg = 0.f;
  float* outp = dir ? outb : outf;
  const int hoff = ks * 36;
  __syncthreads();

  int buf = 0;
  for (int s = 0; s < L_; ++s) {
    const int l = dir ? (L_ - 1 - s) : s;
    const float gxv = gx[(size_t)(b * L_ + l) * 2048 + dir * 1024 + ks * 256 + j];
    float a0 = 0.f, a1 = 0.f, a2 = 0.f, a3 = 0.f;
    const unsigned* hp = &h_pack[buf][hoff];
    #pragma unroll
    for (int q = 0; q < 8; ++q) {
      uint4 hv = *(const uint4*)(hp + q * 4);
      uint4 wv = *(const uint4*)((const char*)w_lds + (q * 16384 + wswz));
      a0 = dot2f(w0[q*4+0], hv.x, a0); a1 = dot2f(w1[q*4+0], hv.x, a1);
      a2 = dot2f(w2[q*4+0], hv.x, a2); a3 = dot2f(wv.x,      hv.x, a3);
      a0 = dot2f(w0[q*4+1], hv.y, a0); a1 = dot2f(w1[q*4+1], hv.y, a1);
      a2 = dot2f(w2[q*4+1], hv.y, a2); a3 = dot2f(wv.y,      hv.y, a3);
      a0 = dot2f(w0[q*4+2], hv.z, a0); a1 = dot2f(w1[q*4+2], hv.z, a1);
      a2 = dot2f(w2[q*4+2], hv.z, a2); a3 = dot2f(wv.z,      hv.z, a3);
      a0 = dot2f(w0[q*4+3], hv.w, a0); a1 = dot2f(w1[q*4+3], hv.w, a1);
      a2 = dot2f(w2[q*4+3], hv.w, a2); a3 = dot2f(wv.w,      hv.w, a3);
    }
    a0 += (ks == 0) ? gxv : 0.f;
    a1 += (ks == 1) ? gxv : 0.f;
    a2 += (ks == 2) ? gxv : 0.f;
    a3 += (ks == 3) ? gxv : 0.f;
    a0 += __shfl_xor(a0, 1, 64); a0 += __shfl_xor(a0, 2, 64);
    a1 += __shfl_xor(a1, 1, 64); a1 += __shfl_xor(a1, 2, 64);
    a2 += __shfl_xor(a2, 1, 64); a2 += __shfl_xor(a2, 2, 64);
    a3 += __shfl_xor(a3, 1, 64); a3 += __shfl_xor(a3, 2, 64);
    const float si = fast_sigmoid(a0);
    const float sf = fast_sigmoid(a1);
    const float tg = fast_tanh(a2);
    const float so = fast_sigmoid(a3);
    c_reg = fmaf(sf, c_reg, si * tg);
    const float hv = so * fast_tanh(c_reg);
    if (ks == 0) outp[(size_t)(b * L_ + l) * H2 + j] = hv;
    const float hpart = __shfl_xor(hv, 4, 64);
    buf ^= 1;
    if (ks == 0 && (j & 1) == 0) {
      const int p = j >> 1;
      h_pack[buf][(p >> 5) * 36 + (p & 31)] = packf16(hv, hpart);
    }
    __syncthreads();
  }
}

extern "C" void kernel_launch(void* const* d_in, const int* in_sizes, int n_in,
                              void* d_out, int out_size, void* d_ws, size_t ws_size,
                              hipStream_t stream)
{
  const float* x    = (const float*)d_in[0];
  const float* wi   = (const float*)d_in[1];
  const float* cw   = (const float*)d_in[2];
  const float* cb   = (const float*)d_in[3];
  const float* xpw  = (const float*)d_in[4];
  const float* dw   = (const float*)d_in[5];
  const float* db   = (const float*)d_in[6];
  const float* Alog = (const float*)d_in[7];
  const float* Dp   = (const float*)d_in[8];
  const float* wo   = (const float*)d_in[9];
  const float* lng  = (const float*)d_in[10];
  const float* lnb  = (const float*)d_in[11];
  const float* wih  = (const float*)d_in[12];
  const float* whh  = (const float*)d_in[13];
  const float* bih  = (const float*)d_in[14];
  const float* bhh  = (const float*)d_in[15];
  const float* fw   = (const float*)d_in[16];
  const float* fb   = (const float*)d_in[17];
  float* out = (float*)d_out;

  float* F    = (float*)d_ws;
  float* xz   = F;                 // 4,194,304 floats (B*L*2048); aliased with gx
  float* gx   = F;                 // LSTM gate precompute, consumed before mamba chain
  float* u    = F + 4194304;       // 2,097,152
  float* xdbl = F + 6291456;       //   131,072
  float* dt   = F + 6422528;       // 2,097,152
  float* ybuf = F + 8519680;       // 2,097,152
  float* mo   = F + 10616832;      // 1,048,576
  float* mbuf = F + 11665408;      // 1,048,576
  float* lf   = F + 12713984;      //   524,288
  float* lb   = F + 13238272;      //   524,288

  const int M = B_ * L_;           // 2048
  dim3 blk(256);

  // LSTM input projection for both dirs + both biases in one GEMM:
  // gx[(b,l)][dir*1024 + j] = x @ wih_all^T + bih + bhh
  gemm_nt<0,false><<<dim3(2048/64, M/64), blk, 0, stream>>>(
      x, wih, gx, M, 2048, 512, 512, 512, 2048, bih, bhh);
  lstm_rec<<<dim3(8), dim3(1024), 0, stream>>>(gx, whh, lf, lb);

  for (int i = 0; i < NL; ++i) {
    const float* min = (i == 0) ? x : mbuf;
    // xz = m @ in_proj_w^T
    gemm_nt<0,false><<<dim3(2048/64, M/64), blk, 0, stream>>>(
        min, wi + (size_t)i*2048*512, xz, M, 2048, 512, 512, 512, 2048, nullptr, nullptr);
    // u = silu(causal depthwise conv(xin) + cb)
    conv_silu<<<dim3((M*DIN)/256), blk, 0, stream>>>(
        xz, cw + (size_t)i*DIN*DCV, cb + i*DIN, u);
    // xdbl = u @ x_proj_w^T
    gemm_nt<0,false><<<dim3(1, M/64), blk, 0, stream>>>(
        u, xpw + (size_t)i*64*1024, xdbl, M, 64, 1024, 1024, 1024, 64, nullptr, nullptr);
    // dt = softplus(dt_in @ dt_proj_w^T + db)
    gemm_nt<1,false><<<dim3(1024/64, M/64), blk, 0, stream>>>(
        xdbl, dw + (size_t)i*1024*32, dt, M, 1024, 32, 64, 32, 1024, db + i*1024, nullptr);
    // selective scan + D skip + gate by silu(z)
    scan_kernel<<<dim3((B_*DIN*DST)/256), blk, 0, stream>>>(
        dt, u, xdbl, xz, Alog + (size_t)i*DIN*DST, Dp + i*DIN, ybuf);
    // mo = y @ out_proj_w^T
    gemm_nt<0,false><<<dim3(512/64, M/64), blk, 0, stream>>>(
        ybuf, wo + (size_t)i*512*1024, mo, M, 512, 1024, 1024, 1024, 512, nullptr, nullptr);
    // m = layernorm(m + mo)
    resid_ln<<<dim3(M), dim3(64), 0, stream>>>(
        min, mo, lng + i*512, lnb + i*512, mbuf);
  }

  // fusion: out = [m | lf | lb] @ fusion_w^T + fb, as 3 K-split GEMM passes
  gemm_nt<0,false><<<dim3(512/64, M/64), blk, 0, stream>>>(
      mbuf, fw,       out, M, 512, 512, 512, 1024, 512, fb, nullptr);
  gemm_nt<0,true><<<dim3(512/64, M/64), blk, 0, stream>>>(
      lf,   fw + 512, out, M, 512, 256, 256, 1024, 512, nullptr, nullptr);
  gemm_nt<0,true><<<dim3(512/64, M/64), blk, 0, stream>>>(
      lb,   fw + 768, out, M, 512, 256, 256, 1024, 512, nullptr, nullptr);
}

// Round 4
// 2652.001 us; speedup vs baseline: 6.2158x; 1.1226x over previous
//
#include <hip/hip_runtime.h>
#include <math.h>

#define B_  4
#define L_  512
#define D_  512
#define DIN 1024
#define DST 16
#define DCV 4
#define DTR 32
#define NL  3
#define H2  256

typedef _Float16 __f16;
typedef __f16 f16x2 __attribute__((ext_vector_type(2)));
typedef __f16 half8 __attribute__((ext_vector_type(8)));
typedef float f32x4v __attribute__((ext_vector_type(4)));
typedef unsigned uint4v __attribute__((ext_vector_type(4)));

__device__ __forceinline__ float fast_sigmoid(float x) { return 1.f / (1.f + __expf(-x)); }
__device__ __forceinline__ float fast_tanh(float x) { return 2.f / (1.f + __expf(-2.f * x)) - 1.f; }

__device__ __forceinline__ float dot2f(unsigned a, unsigned b, float c) {
  return __builtin_amdgcn_fdot2(__builtin_bit_cast(f16x2, a),
                                __builtin_bit_cast(f16x2, b), c, false);
}
__device__ __forceinline__ unsigned packf16(float a, float b) {
  f16x2 p; p.x = (__f16)a; p.y = (__f16)b;
  return __builtin_bit_cast(unsigned, p);
}

// ---------------- f16 MFMA GEMM: C[M,N] = A[M,K] @ W[N,K]^T (+bias +bias2) ----------------
// Requires M%128==0, N%128==0, K%64==0. 128x128 tile, BK=64, 4 waves (2x2), f16 inputs.
template<bool ACC>
__global__ __launch_bounds__(256) void gemm_mfma(
    const float* __restrict__ A, const float* __restrict__ W, float* __restrict__ C,
    int M, int N, int K, int lda, int ldb, int ldc,
    const float* __restrict__ bias, const float* __restrict__ bias2)
{
  __shared__ uint4v As[1024];   // [row][8 kb-slots], phys slot = kb ^ (row&7), 16KB
  __shared__ uint4v Bs[1024];   // 16KB
  const int tid  = threadIdx.x;
  const int lane = tid & 63, wid = tid >> 6;
  const int wr = wid >> 1, wc = wid & 1;       // wave grid 2x2
  const int fr = lane & 15, fq = lane >> 4;    // frag row/col, k-quarter
  const int m0 = blockIdx.y * 128, n0 = blockIdx.x * 128;
  const int srow = tid >> 3, skb = tid & 7;    // staging: slot s covers (row, kb)

  f32x4v acc[4][4] = {};
  for (int k0 = 0; k0 < K; k0 += 64) {
    const float* Abase = A + (size_t)m0 * lda + k0;
    const float* Bbase = W + (size_t)n0 * ldb + k0;
    #pragma unroll
    for (int i = 0; i < 4; ++i) {
      int row = srow + i * 32;
      const float4* pa = (const float4*)(Abase + (size_t)row * lda + skb * 8);
      const float4* pb = (const float4*)(Bbase + (size_t)row * ldb + skb * 8);
      float4 a0 = pa[0], a1 = pa[1];
      float4 b0 = pb[0], b1 = pb[1];
      uint4v ap, bp;
      ap.x = packf16(a0.x, a0.y); ap.y = packf16(a0.z, a0.w);
      ap.z = packf16(a1.x, a1.y); ap.w = packf16(a1.z, a1.w);
      bp.x = packf16(b0.x, b0.y); bp.y = packf16(b0.z, b0.w);
      bp.z = packf16(b1.x, b1.y); bp.w = packf16(b1.z, b1.w);
      As[row * 8 + (skb ^ (row & 7))] = ap;
      Bs[row * 8 + (skb ^ (row & 7))] = bp;
    }
    __syncthreads();
    #pragma unroll
    for (int ks = 0; ks < 2; ++ks) {
      half8 af[4], bf[4];
      #pragma unroll
      for (int mt = 0; mt < 4; ++mt) {
        int row = wr * 64 + mt * 16 + fr;
        int kb = ks * 4 + fq;
        af[mt] = __builtin_bit_cast(half8, As[row * 8 + (kb ^ (row & 7))]);
      }
      #pragma unroll
      for (int nt = 0; nt < 4; ++nt) {
        int row = wc * 64 + nt * 16 + fr;
        int kb = ks * 4 + fq;
        bf[nt] = __builtin_bit_cast(half8, Bs[row * 8 + (kb ^ (row & 7))]);
      }
      #pragma unroll
      for (int mt = 0; mt < 4; ++mt)
        #pragma unroll
        for (int nt = 0; nt < 4; ++nt)
          acc[mt][nt] = __builtin_amdgcn_mfma_f32_16x16x32_f16(af[mt], bf[nt], acc[mt][nt], 0, 0, 0);
    }
    __syncthreads();
  }
  // epilogue: D row m = fq*4 + r, col n = fr
  #pragma unroll
  for (int nt = 0; nt < 4; ++nt) {
    int n = n0 + wc * 64 + nt * 16 + fr;
    float bv = (bias ? bias[n] : 0.f) + (bias2 ? bias2[n] : 0.f);
    #pragma unroll
    for (int mt = 0; mt < 4; ++mt) {
      #pragma unroll
      for (int r = 0; r < 4; ++r) {
        int m = m0 + wr * 64 + mt * 16 + fq * 4 + r;
        float v = acc[mt][nt][r] + bv;
        if (ACC) C[(size_t)m * ldc + n] += v; else C[(size_t)m * ldc + n] = v;
      }
    }
  }
}

// ---------------- fp32 fallback GEMM (small/odd shapes) ----------------
// C[M,N] = act(A[M,K] @ B[N,K]^T + bias); ACT: 0 = none, 1 = softplus
template<int ACT>
__global__ __launch_bounds__(256) void gemm_nt(
    const float* __restrict__ A, const float* __restrict__ Bm, float* __restrict__ C,
    int M, int N, int K, int lda, int ldb, int ldc,
    const float* __restrict__ bias)
{
  __shared__ __align__(16) float As[16][64];
  __shared__ __align__(16) float Bs[16][64];
  const int tid = threadIdx.x;
  const int tx = tid & 15, ty = tid >> 4;
  const int m0 = blockIdx.y * 64, n0 = blockIdx.x * 64;
  const int r = tid >> 2, kq = (tid & 3) * 4;
  float acc[4][4] = {};
  for (int k0 = 0; k0 < K; k0 += 16) {
    float4 av = *(const float4*)(A  + (size_t)(m0 + r) * lda + (k0 + kq));
    float4 bv = *(const float4*)(Bm + (size_t)(n0 + r) * ldb + (k0 + kq));
    As[kq+0][r] = av.x; As[kq+1][r] = av.y; As[kq+2][r] = av.z; As[kq+3][r] = av.w;
    Bs[kq+0][r] = bv.x; Bs[kq+1][r] = bv.y; Bs[kq+2][r] = bv.z; Bs[kq+3][r] = bv.w;
    __syncthreads();
    #pragma unroll
    for (int kk = 0; kk < 16; ++kk) {
      float4 a = *(const float4*)(&As[kk][ty*4]);
      float4 b = *(const float4*)(&Bs[kk][tx*4]);
      float aa[4] = {a.x, a.y, a.z, a.w};
      float bb[4] = {b.x, b.y, b.z, b.w};
      #pragma unroll
      for (int i = 0; i < 4; ++i)
        #pragma unroll
        for (int j = 0; j < 4; ++j)
          acc[i][j] = fmaf(aa[i], bb[j], acc[i][j]);
    }
    __syncthreads();
  }
  #pragma unroll
  for (int i = 0; i < 4; ++i) {
    int m = m0 + ty*4 + i;
    float* cp = C + (size_t)m * ldc + n0 + tx*4;
    #pragma unroll
    for (int j = 0; j < 4; ++j) {
      int n = n0 + tx*4 + j;
      float v = acc[i][j];
      if (bias)  v += bias[n];
      if (ACT == 1) v = (v > 20.f) ? v : log1pf(__expf(v));
      cp[j] = v;
    }
  }
}

// u[b,l,c] = silu(cb[c] + sum_k xin[b,l-3+k,c] * cw[c,k]), xin = xz[:, :, :1024]
__global__ __launch_bounds__(256) void conv_silu(
    const float* __restrict__ xz, const float* __restrict__ cw, const float* __restrict__ cb,
    float* __restrict__ u)
{
  int t = blockIdx.x * 256 + threadIdx.x;   // over B*L*DIN
  int c  = t & (DIN - 1);
  int bl = t >> 10;
  int l  = bl & (L_ - 1);
  float acc = cb[c];
  #pragma unroll
  for (int k = 0; k < DCV; ++k) {
    int ls = l + k - (DCV - 1);
    if (ls >= 0)
      acc = fmaf(xz[(size_t)(bl + k - (DCV - 1)) * 2048 + c], cw[c * DCV + k], acc);
  }
  u[t] = acc * fast_sigmoid(acc);
}

// selective scan: one thread per (b, c, n); n in low 4 bits of lane -> shfl_xor reduce
__global__ __launch_bounds__(256) void scan_kernel(
    const float* __restrict__ dt, const float* __restrict__ u,
    const float* __restrict__ xdbl, const float* __restrict__ xz,
    const float* __restrict__ A_log, const float* __restrict__ Dp,
    float* __restrict__ y)
{
  int t = blockIdx.x * 256 + threadIdx.x;   // [0, B*DIN*DST)
  int n  = t & 15;
  int bc = t >> 4;
  int c  = bc & (DIN - 1);
  int b  = bc >> 10;
  float Ac = -__expf(A_log[c * DST + n]);
  float Dc = Dp[c];
  float h = 0.f;
  for (int l = 0; l < L_; ++l) {
    size_t base = (size_t)(b * L_ + l);
    float dtv = dt[base * DIN + c];
    float uv  = u [base * DIN + c];
    float Bn  = xdbl[base * 64 + 32 + n];
    float Cn  = xdbl[base * 64 + 48 + n];
    float dA  = __expf(dtv * Ac);
    float du  = dtv * uv;
    h = fmaf(dA, h, du * Bn);
    float p = h * Cn;
    p += __shfl_xor(p, 1, 64);
    p += __shfl_xor(p, 2, 64);
    p += __shfl_xor(p, 4, 64);
    p += __shfl_xor(p, 8, 64);
    if (n == 0) {
      float zv = xz[base * 2048 + 1024 + c];
      float yv = p + uv * Dc;
      yv *= zv * fast_sigmoid(zv);
      y[base * DIN + c] = yv;
    }
  }
}

// m_out[row] = layernorm(a[row] + mo[row]) * g + b   (row length 512, one wave per row)
__global__ __launch_bounds__(64) void resid_ln(
    const float* __restrict__ a, const float* __restrict__ mo,
    const float* __restrict__ g, const float* __restrict__ bta,
    float* __restrict__ outm)
{
  int row = blockIdx.x;
  int lane = threadIdx.x;
  const float* pa = a  + (size_t)row * 512;
  const float* pb = mo + (size_t)row * 512;
  float v[8];
  float s = 0.f, s2 = 0.f;
  #pragma unroll
  for (int i = 0; i < 8; ++i) {
    float x = pa[lane + i * 64] + pb[lane + i * 64];
    v[i] = x; s += x; s2 += x * x;
  }
  #pragma unroll
  for (int off = 1; off < 64; off <<= 1) {
    s  += __shfl_xor(s,  off, 64);
    s2 += __shfl_xor(s2, off, 64);
  }
  float mean = s * (1.f / 512.f);
  float var  = s2 * (1.f / 512.f) - mean * mean;
  float rstd = rsqrtf(var + 1e-5f);
  #pragma unroll
  for (int i = 0; i < 8; ++i) {
    int cidx = lane + i * 64;
    outm[(size_t)row * 512 + cidx] = (v[i] - mean) * rstd * g[cidx] + bta[cidx];
  }
}

// LSTM recurrence. Block per (dir,b), 1024 threads = (unit j) x (k-slice ks in [0,4)).
// Weights f16-packed: gates i,f,g in VGPR (96 dwords/thread), gate o in LDS (128KB).
// __launch_bounds__(1024,4): 4 waves/EU min -> 128-VGPR cap, weight arrays stay in regs.
__global__ __launch_bounds__(1024, 4) void lstm_rec(
    const float* __restrict__ gx, const float* __restrict__ whh,
    float* __restrict__ outf, float* __restrict__ outb)
{
  __shared__ uint4 w_lds[8 * 1024];                 // 128KB o-gate weights
  __shared__ __align__(16) unsigned h_pack[2][144]; // 2 x (4 groups x 36 dwords)
  const int dir = blockIdx.x >> 2, b = blockIdx.x & 3;
  const int t = threadIdx.x;
  const int j = t >> 2, ks = t & 3;
  const size_t wbase = (size_t)dir * 1024 * 256;
  const unsigned wswz = (unsigned)((t * 16) ^ (((t >> 3) & 3) << 4));

  unsigned w0[32], w1[32], w2[32];
#define LOADW(warr, grow)                                                     \
  { const float* wr = whh + wbase + (size_t)((grow) * 256 + j) * 256 + ks*64; \
    _Pragma("unroll")                                                         \
    for (int q = 0; q < 16; ++q) {                                            \
      float4 f = ((const float4*)wr)[q];                                      \
      warr[q*2]   = packf16(f.x, f.y);                                        \
      warr[q*2+1] = packf16(f.z, f.w);                                        \
    } }
  LOADW(w0, 0)
  LOADW(w1, 1)
  LOADW(w2, 2)
#undef LOADW
  {
    const float* wr = whh + wbase + (size_t)(768 + j) * 256 + ks * 64;
    #pragma unroll
    for (int q = 0; q < 8; ++q) {
      float4 fa = ((const float4*)wr)[q*2];
      float4 fb = ((const float4*)wr)[q*2+1];
      uint4 pk;
      pk.x = packf16(fa.x, fa.y); pk.y = packf16(fa.z, fa.w);
      pk.z = packf16(fb.x, fb.y); pk.w = packf16(fb.z, fb.w);
      *(uint4*)((char*)w_lds + (q * 16384 + wswz)) = pk;
    }
  }
  if (t < 288) ((unsigned*)h_pack)[t] = 0u;
  float c_reg = 0.f;
  float* outp = dir ? outb : outf;
  const int hoff = ks * 36;
  __syncthreads();

  int buf = 0;
  float gxv = gx[(size_t)(b * L_ + (dir ? L_ - 1 : 0)) * 2048 + dir * 1024 + ks * 256 + j];
  for (int s = 0; s < L_; ++s) {
    const int l = dir ? (L_ - 1 - s) : s;
    float gxv_next = 0.f;
    if (s + 1 < L_) {
      const int ln = dir ? (L_ - 2 - s) : (s + 1);
      gxv_next = gx[(size_t)(b * L_ + ln) * 2048 + dir * 1024 + ks * 256 + j];
    }
    float a0 = 0.f, a1 = 0.f, a2 = 0.f, a3 = 0.f;
    const unsigned* hp = &h_pack[buf][hoff];
    #pragma unroll
    for (int q = 0; q < 8; ++q) {
      uint4 hv = *(const uint4*)(hp + q * 4);
      uint4 wv = *(const uint4*)((const char*)w_lds + (q * 16384 + wswz));
      a0 = dot2f(w0[q*4+0], hv.x, a0); a1 = dot2f(w1[q*4+0], hv.x, a1);
      a2 = dot2f(w2[q*4+0], hv.x, a2); a3 = dot2f(wv.x,      hv.x, a3);
      a0 = dot2f(w0[q*4+1], hv.y, a0); a1 = dot2f(w1[q*4+1], hv.y, a1);
      a2 = dot2f(w2[q*4+1], hv.y, a2); a3 = dot2f(wv.y,      hv.y, a3);
      a0 = dot2f(w0[q*4+2], hv.z, a0); a1 = dot2f(w1[q*4+2], hv.z, a1);
      a2 = dot2f(w2[q*4+2], hv.z, a2); a3 = dot2f(wv.z,      hv.z, a3);
      a0 = dot2f(w0[q*4+3], hv.w, a0); a1 = dot2f(w1[q*4+3], hv.w, a1);
      a2 = dot2f(w2[q*4+3], hv.w, a2); a3 = dot2f(wv.w,      hv.w, a3);
    }
    a0 += (ks == 0) ? gxv : 0.f;
    a1 += (ks == 1) ? gxv : 0.f;
    a2 += (ks == 2) ? gxv : 0.f;
    a3 += (ks == 3) ? gxv : 0.f;
    a0 += __shfl_xor(a0, 1, 64); a0 += __shfl_xor(a0, 2, 64);
    a1 += __shfl_xor(a1, 1, 64); a1 += __shfl_xor(a1, 2, 64);
    a2 += __shfl_xor(a2, 1, 64); a2 += __shfl_xor(a2, 2, 64);
    a3 += __shfl_xor(a3, 1, 64); a3 += __shfl_xor(a3, 2, 64);
    const float si = fast_sigmoid(a0);
    const float sf = fast_sigmoid(a1);
    const float tg = fast_tanh(a2);
    const float so = fast_sigmoid(a3);
    c_reg = fmaf(sf, c_reg, si * tg);
    const float hv = so * fast_tanh(c_reg);
    if (ks == 0) outp[(size_t)(b * L_ + l) * H2 + j] = hv;
    const float hpart = __shfl_xor(hv, 4, 64);
    buf ^= 1;
    if (ks == 0 && (j & 1) == 0) {
      const int p = j >> 1;
      h_pack[buf][(p >> 5) * 36 + (p & 31)] = packf16(hv, hpart);
    }
    gxv = gxv_next;
    __syncthreads();
  }
}

extern "C" void kernel_launch(void* const* d_in, const int* in_sizes, int n_in,
                              void* d_out, int out_size, void* d_ws, size_t ws_size,
                              hipStream_t stream)
{
  const float* x    = (const float*)d_in[0];
  const float* wi   = (const float*)d_in[1];
  const float* cw   = (const float*)d_in[2];
  const float* cb   = (const float*)d_in[3];
  const float* xpw  = (const float*)d_in[4];
  const float* dw   = (const float*)d_in[5];
  const float* db   = (const float*)d_in[6];
  const float* Alog = (const float*)d_in[7];
  const float* Dp   = (const float*)d_in[8];
  const float* wo   = (const float*)d_in[9];
  const float* lng  = (const float*)d_in[10];
  const float* lnb  = (const float*)d_in[11];
  const float* wih  = (const float*)d_in[12];
  const float* whh  = (const float*)d_in[13];
  const float* bih  = (const float*)d_in[14];
  const float* bhh  = (const float*)d_in[15];
  const float* fw   = (const float*)d_in[16];
  const float* fb   = (const float*)d_in[17];
  float* out = (float*)d_out;

  float* F    = (float*)d_ws;
  float* xz   = F;                 // 4,194,304 floats (B*L*2048); aliased with gx
  float* gx   = F;                 // LSTM gate precompute, consumed before mamba chain
  float* u    = F + 4194304;       // 2,097,152
  float* xdbl = F + 6291456;       //   131,072
  float* dt   = F + 6422528;       // 2,097,152
  float* ybuf = F + 8519680;       // 2,097,152
  float* mo   = F + 10616832;      // 1,048,576
  float* mbuf = F + 11665408;      // 1,048,576
  float* lf   = F + 12713984;      //   524,288
  float* lb   = F + 13238272;      //   524,288

  const int M = B_ * L_;           // 2048
  dim3 blk(256);

  // LSTM input projection for both dirs + both biases in one GEMM (f16 MFMA):
  gemm_mfma<false><<<dim3(2048/128, M/128), blk, 0, stream>>>(
      x, wih, gx, M, 2048, 512, 512, 512, 2048, bih, bhh);
  lstm_rec<<<dim3(8), dim3(1024), 0, stream>>>(gx, whh, lf, lb);

  for (int i = 0; i < NL; ++i) {
    const float* min = (i == 0) ? x : mbuf;
    // xz = m @ in_proj_w^T  (MFMA)
    gemm_mfma<false><<<dim3(2048/128, M/128), blk, 0, stream>>>(
        min, wi + (size_t)i*2048*512, xz, M, 2048, 512, 512, 512, 2048, nullptr, nullptr);
    // u = silu(causal depthwise conv(xin) + cb)
    conv_silu<<<dim3((M*DIN)/256), blk, 0, stream>>>(
        xz, cw + (size_t)i*DIN*DCV, cb + i*DIN, u);
    // xdbl = u @ x_proj_w^T  (N=64 -> fp32 path)
    gemm_nt<0><<<dim3(1, M/64), blk, 0, stream>>>(
        u, xpw + (size_t)i*64*1024, xdbl, M, 64, 1024, 1024, 1024, 64, nullptr);
    // dt = softplus(dt_in @ dt_proj_w^T + db)  (K=32 -> fp32 path)
    gemm_nt<1><<<dim3(1024/64, M/64), blk, 0, stream>>>(
        xdbl, dw + (size_t)i*1024*32, dt, M, 1024, 32, 64, 32, 1024, db + i*1024);
    // selective scan + D skip + gate by silu(z)
    scan_kernel<<<dim3((B_*DIN*DST)/256), blk, 0, stream>>>(
        dt, u, xdbl, xz, Alog + (size_t)i*DIN*DST, Dp + i*DIN, ybuf);
    // mo = y @ out_proj_w^T  (MFMA)
    gemm_mfma<false><<<dim3(512/128, M/128), blk, 0, stream>>>(
        ybuf, wo + (size_t)i*512*1024, mo, M, 512, 1024, 1024, 1024, 512, nullptr, nullptr);
    // m = layernorm(m + mo)
    resid_ln<<<dim3(M), dim3(64), 0, stream>>>(
        min, mo, lng + i*512, lnb + i*512, mbuf);
  }

  // fusion: out = [m | lf | lb] @ fusion_w^T + fb, as 3 K-split MFMA passes
  gemm_mfma<false><<<dim3(512/128, M/128), blk, 0, stream>>>(
      mbuf, fw,       out, M, 512, 512, 512, 1024, 512, fb, nullptr);
  gemm_mfma<true><<<dim3(512/128, M/128), blk, 0, stream>>>(
      lf,   fw + 512, out, M, 512, 256, 256, 1024, 512, nullptr, nullptr);
  gemm_mfma<true><<<dim3(512/128, M/128), blk, 0, stream>>>(
      lb,   fw + 768, out, M, 512, 256, 256, 1024, 512, nullptr, nullptr);
}

// Round 5
// 1842.426 us; speedup vs baseline: 8.9471x; 1.4394x over previous
//
#include <hip/hip_runtime.h>
#include <math.h>

#define B_  4
#define L_  512
#define D_  512
#define DIN 1024
#define DST 16
#define DCV 4
#define DTR 32
#define NL  3
#define H2  256

typedef _Float16 __f16;
typedef __f16 f16x2 __attribute__((ext_vector_type(2)));
typedef __f16 half8 __attribute__((ext_vector_type(8)));
typedef float f32x4v __attribute__((ext_vector_type(4)));
typedef unsigned uint4v __attribute__((ext_vector_type(4)));

__device__ __forceinline__ float fast_sigmoid(float x) { return 1.f / (1.f + __expf(-x)); }
__device__ __forceinline__ float fast_tanh(float x) { return 2.f / (1.f + __expf(-2.f * x)) - 1.f; }

__device__ __forceinline__ float dot2f(unsigned a, unsigned b, float c) {
  return __builtin_amdgcn_fdot2(__builtin_bit_cast(f16x2, a),
                                __builtin_bit_cast(f16x2, b), c, false);
}
__device__ __forceinline__ unsigned packf16(float a, float b) {
  f16x2 p; p.x = (__f16)a; p.y = (__f16)b;
  return __builtin_bit_cast(unsigned, p);
}

// ---------------- f16 MFMA GEMM: C[M,N] = A[M,K] @ W[N,K]^T (+bias +bias2) ----------------
// Requires M%128==0, N%128==0, K%64==0. 128x128 tile, BK=64, 4 waves (2x2), f16 inputs.
template<bool ACC>
__global__ __launch_bounds__(256) void gemm_mfma(
    const float* __restrict__ A, const float* __restrict__ W, float* __restrict__ C,
    int M, int N, int K, int lda, int ldb, int ldc,
    const float* __restrict__ bias, const float* __restrict__ bias2)
{
  __shared__ uint4v As[1024];   // [row][8 kb-slots], phys slot = kb ^ (row&7), 16KB
  __shared__ uint4v Bs[1024];   // 16KB
  const int tid  = threadIdx.x;
  const int lane = tid & 63, wid = tid >> 6;
  const int wr = wid >> 1, wc = wid & 1;       // wave grid 2x2
  const int fr = lane & 15, fq = lane >> 4;    // frag row/col, k-quarter
  const int m0 = blockIdx.y * 128, n0 = blockIdx.x * 128;
  const int srow = tid >> 3, skb = tid & 7;    // staging: slot s covers (row, kb)

  f32x4v acc[4][4] = {};
  for (int k0 = 0; k0 < K; k0 += 64) {
    const float* Abase = A + (size_t)m0 * lda + k0;
    const float* Bbase = W + (size_t)n0 * ldb + k0;
    #pragma unroll
    for (int i = 0; i < 4; ++i) {
      int row = srow + i * 32;
      const float4* pa = (const float4*)(Abase + (size_t)row * lda + skb * 8);
      const float4* pb = (const float4*)(Bbase + (size_t)row * ldb + skb * 8);
      float4 a0 = pa[0], a1 = pa[1];
      float4 b0 = pb[0], b1 = pb[1];
      uint4v ap, bp;
      ap.x = packf16(a0.x, a0.y); ap.y = packf16(a0.z, a0.w);
      ap.z = packf16(a1.x, a1.y); ap.w = packf16(a1.z, a1.w);
      bp.x = packf16(b0.x, b0.y); bp.y = packf16(b0.z, b0.w);
      bp.z = packf16(b1.x, b1.y); bp.w = packf16(b1.z, b1.w);
      As[row * 8 + (skb ^ (row & 7))] = ap;
      Bs[row * 8 + (skb ^ (row & 7))] = bp;
    }
    __syncthreads();
    #pragma unroll
    for (int ks = 0; ks < 2; ++ks) {
      half8 af[4], bf[4];
      #pragma unroll
      for (int mt = 0; mt < 4; ++mt) {
        int row = wr * 64 + mt * 16 + fr;
        int kb = ks * 4 + fq;
        af[mt] = __builtin_bit_cast(half8, As[row * 8 + (kb ^ (row & 7))]);
      }
      #pragma unroll
      for (int nt = 0; nt < 4; ++nt) {
        int row = wc * 64 + nt * 16 + fr;
        int kb = ks * 4 + fq;
        bf[nt] = __builtin_bit_cast(half8, Bs[row * 8 + (kb ^ (row & 7))]);
      }
      #pragma unroll
      for (int mt = 0; mt < 4; ++mt)
        #pragma unroll
        for (int nt = 0; nt < 4; ++nt)
          acc[mt][nt] = __builtin_amdgcn_mfma_f32_16x16x32_f16(af[mt], bf[nt], acc[mt][nt], 0, 0, 0);
    }
    __syncthreads();
  }
  #pragma unroll
  for (int nt = 0; nt < 4; ++nt) {
    int n = n0 + wc * 64 + nt * 16 + fr;
    float bv = (bias ? bias[n] : 0.f) + (bias2 ? bias2[n] : 0.f);
    #pragma unroll
    for (int mt = 0; mt < 4; ++mt) {
      #pragma unroll
      for (int r = 0; r < 4; ++r) {
        int m = m0 + wr * 64 + mt * 16 + fq * 4 + r;
        float v = acc[mt][nt][r] + bv;
        if (ACC) C[(size_t)m * ldc + n] += v; else C[(size_t)m * ldc + n] = v;
      }
    }
  }
}

// ---------------- fp32 fallback GEMM (small/odd shapes) ----------------
template<int ACT>
__global__ __launch_bounds__(256) void gemm_nt(
    const float* __restrict__ A, const float* __restrict__ Bm, float* __restrict__ C,
    int M, int N, int K, int lda, int ldb, int ldc,
    const float* __restrict__ bias)
{
  __shared__ __align__(16) float As[16][64];
  __shared__ __align__(16) float Bs[16][64];
  const int tid = threadIdx.x;
  const int tx = tid & 15, ty = tid >> 4;
  const int m0 = blockIdx.y * 64, n0 = blockIdx.x * 64;
  const int r = tid >> 2, kq = (tid & 3) * 4;
  float acc[4][4] = {};
  for (int k0 = 0; k0 < K; k0 += 16) {
    float4 av = *(const float4*)(A  + (size_t)(m0 + r) * lda + (k0 + kq));
    float4 bv = *(const float4*)(Bm + (size_t)(n0 + r) * ldb + (k0 + kq));
    As[kq+0][r] = av.x; As[kq+1][r] = av.y; As[kq+2][r] = av.z; As[kq+3][r] = av.w;
    Bs[kq+0][r] = bv.x; Bs[kq+1][r] = bv.y; Bs[kq+2][r] = bv.z; Bs[kq+3][r] = bv.w;
    __syncthreads();
    #pragma unroll
    for (int kk = 0; kk < 16; ++kk) {
      float4 a = *(const float4*)(&As[kk][ty*4]);
      float4 b = *(const float4*)(&Bs[kk][tx*4]);
      float aa[4] = {a.x, a.y, a.z, a.w};
      float bb[4] = {b.x, b.y, b.z, b.w};
      #pragma unroll
      for (int i = 0; i < 4; ++i)
        #pragma unroll
        for (int j = 0; j < 4; ++j)
          acc[i][j] = fmaf(aa[i], bb[j], acc[i][j]);
    }
    __syncthreads();
  }
  #pragma unroll
  for (int i = 0; i < 4; ++i) {
    int m = m0 + ty*4 + i;
    float* cp = C + (size_t)m * ldc + n0 + tx*4;
    #pragma unroll
    for (int j = 0; j < 4; ++j) {
      int n = n0 + tx*4 + j;
      float v = acc[i][j];
      if (bias)  v += bias[n];
      if (ACT == 1) v = (v > 20.f) ? v : log1pf(__expf(v));
      cp[j] = v;
    }
  }
}

// xpw_pad[r][k] = r<64 ? xpw[r][k] : 0   (128x1024)
__global__ __launch_bounds__(256) void pad_xpw(
    const float* __restrict__ src, float* __restrict__ dst)
{
  int t = blockIdx.x * 256 + threadIdx.x;   // [0, 131072)
  int r = t >> 10;
  dst[t] = (r < 64) ? src[t] : 0.f;
}

// u[b,l,c] = silu(cb[c] + sum_k xin[b,l-3+k,c] * cw[c,k]), xin = xz[:, :, :1024]
__global__ __launch_bounds__(256) void conv_silu(
    const float* __restrict__ xz, const float* __restrict__ cw, const float* __restrict__ cb,
    float* __restrict__ u)
{
  int t = blockIdx.x * 256 + threadIdx.x;   // over B*L*DIN
  int c  = t & (DIN - 1);
  int bl = t >> 10;
  int l  = bl & (L_ - 1);
  float acc = cb[c];
  #pragma unroll
  for (int k = 0; k < DCV; ++k) {
    int ls = l + k - (DCV - 1);
    if (ls >= 0)
      acc = fmaf(xz[(size_t)(bl + k - (DCV - 1)) * 2048 + c], cw[c * DCV + k], acc);
  }
  u[t] = acc * fast_sigmoid(acc);
}

// selective scan: thread per (b,c,n); next-step inputs software-prefetched so the
// only serial per-step dependency is exp+fma. xdbl now has ld 128.
__global__ __launch_bounds__(256) void scan_kernel(
    const float* __restrict__ dt, const float* __restrict__ u,
    const float* __restrict__ xdbl, const float* __restrict__ xz,
    const float* __restrict__ A_log, const float* __restrict__ Dp,
    float* __restrict__ y)
{
  int t = blockIdx.x * 256 + threadIdx.x;   // [0, B*DIN*DST)
  int n  = t & 15;
  int bc = t >> 4;
  int c  = bc & (DIN - 1);
  int b  = bc >> 10;
  float Ac = -__expf(A_log[c * DST + n]);
  float Dc = Dp[c];
  float h = 0.f;
  const size_t row = (size_t)b * L_;
  float dtv = dt[row * DIN + c];
  float uv  = u [row * DIN + c];
  float Bn  = xdbl[row * 128 + 32 + n];
  float Cn  = xdbl[row * 128 + 48 + n];
  float zv  = xz[row * 2048 + 1024 + c];
  for (int l = 0; l < L_; ++l) {
    float dt_n = 0.f, u_n = 0.f, B_n = 0.f, C_n = 0.f, z_n = 0.f;
    if (l + 1 < L_) {
      const size_t nb = row + l + 1;
      dt_n = dt[nb * DIN + c];
      u_n  = u [nb * DIN + c];
      B_n  = xdbl[nb * 128 + 32 + n];
      C_n  = xdbl[nb * 128 + 48 + n];
      z_n  = xz[nb * 2048 + 1024 + c];
    }
    float dA = __expf(dtv * Ac);
    h = fmaf(dA, h, (dtv * uv) * Bn);
    float p = h * Cn;
    p += __shfl_xor(p, 1, 64);
    p += __shfl_xor(p, 2, 64);
    p += __shfl_xor(p, 4, 64);
    p += __shfl_xor(p, 8, 64);
    if (n == 0) {
      float yv = p + uv * Dc;
      yv *= zv * fast_sigmoid(zv);
      y[(row + l) * DIN + c] = yv;
    }
    dtv = dt_n; uv = u_n; Bn = B_n; Cn = C_n; zv = z_n;
  }
}

// m_out[row] = layernorm(a[row] + mo[row]) * g + b   (row length 512, one wave per row)
__global__ __launch_bounds__(64) void resid_ln(
    const float* __restrict__ a, const float* __restrict__ mo,
    const float* __restrict__ g, const float* __restrict__ bta,
    float* __restrict__ outm)
{
  int row = blockIdx.x;
  int lane = threadIdx.x;
  const float* pa = a  + (size_t)row * 512;
  const float* pb = mo + (size_t)row * 512;
  float v[8];
  float s = 0.f, s2 = 0.f;
  #pragma unroll
  for (int i = 0; i < 8; ++i) {
    float x = pa[lane + i * 64] + pb[lane + i * 64];
    v[i] = x; s += x; s2 += x * x;
  }
  #pragma unroll
  for (int off = 1; off < 64; off <<= 1) {
    s  += __shfl_xor(s,  off, 64);
    s2 += __shfl_xor(s2, off, 64);
  }
  float mean = s * (1.f / 512.f);
  float var  = s2 * (1.f / 512.f) - mean * mean;
  float rstd = rsqrtf(var + 1e-5f);
  #pragma unroll
  for (int i = 0; i < 8; ++i) {
    int cidx = lane + i * 64;
    outm[(size_t)row * 512 + cidx] = (v[i] - mean) * rstd * g[cidx] + bta[cidx];
  }
}

// LSTM recurrence. Block per (dir,b), 512 threads = (unit j in [0,256)) x (K-half ks in [0,2)).
// waves_per_eu(2,2) pins 2 waves/EU -> 256-VGPR budget: gates i,f,g (192 dwords f16-packed)
// live in VGPRs; gate o streamed from XOR-swizzled LDS (conflict-free ds_read_b128);
// h packed-f16 in LDS, double-buffered; gx prefetched. One barrier per step.
__global__ __launch_bounds__(512) __attribute__((amdgpu_waves_per_eu(2, 2)))
void lstm_rec(
    const float* __restrict__ gx, const float* __restrict__ whh,
    float* __restrict__ outf, float* __restrict__ outb)
{
  __shared__ uint4 wo_lds[512 * 16];          // 128KB o-gate weights
  __shared__ __align__(16) uint4 h4[2][2][16]; // 2 bufs x 2 K-halves x 128 f16
  const int dir = blockIdx.x >> 2, b = blockIdx.x & 3;
  const int t = threadIdx.x;
  const int j = t >> 1, ks = t & 1;
  const int tm = t & 15;
  const size_t wbase = (size_t)dir * 1024 * 256;
  const int koff = ks * 128;

  // ---- one-time: load + f16-pack weights ----
  unsigned w0[64], w1[64], w2[64];
#define LOADW(warr, grow)                                                      \
  { const float* wr = whh + wbase + (size_t)((grow) * 256 + j) * 256 + koff;   \
    _Pragma("unroll")                                                          \
    for (int q = 0; q < 32; ++q) {                                             \
      float4 f = ((const float4*)wr)[q];                                       \
      warr[q*2]   = packf16(f.x, f.y);                                         \
      warr[q*2+1] = packf16(f.z, f.w);                                         \
    } }
  LOADW(w0, 0)
  LOADW(w1, 1)
  LOADW(w2, 2)
#undef LOADW
  {
    const float* wr = whh + wbase + (size_t)(768 + j) * 256 + koff;
    #pragma unroll
    for (int q = 0; q < 8; ++q) {
      float4 fa = ((const float4*)wr)[q*4+0];
      float4 fb = ((const float4*)wr)[q*4+1];
      float4 fc = ((const float4*)wr)[q*4+2];
      float4 fd = ((const float4*)wr)[q*4+3];
      uint4 p0, p1;
      p0.x = packf16(fa.x, fa.y); p0.y = packf16(fa.z, fa.w);
      p0.z = packf16(fb.x, fb.y); p0.w = packf16(fb.z, fb.w);
      p1.x = packf16(fc.x, fc.y); p1.y = packf16(fc.z, fc.w);
      p1.z = packf16(fd.x, fd.y); p1.w = packf16(fd.z, fd.w);
      wo_lds[t * 16 + ((q*2)   ^ tm)] = p0;
      wo_lds[t * 16 + ((q*2+1) ^ tm)] = p1;
    }
  }
  if (t < 256) ((unsigned*)h4)[t] = 0u;
  float c_reg = 0.f;
  float* outp = dir ? outb : outf;
  const float* gxb = gx + (size_t)(b * L_) * 2048 + dir * 1024;
  const int offA = (ks ? 1 : 0) * 256 + j;   // ks0 -> gate i, ks1 -> gate f
  const int offB = (ks ? 3 : 2) * 256 + j;   // ks0 -> gate g, ks1 -> gate o
  __syncthreads();

  int buf = 0;
  const int l0 = dir ? (L_ - 1) : 0;
  float gA = gxb[(size_t)l0 * 2048 + offA];
  float gB = gxb[(size_t)l0 * 2048 + offB];

  for (int s = 0; s < L_; ++s) {
    const int l = dir ? (L_ - 1 - s) : s;
    float gA_n = 0.f, gB_n = 0.f;
    if (s + 1 < L_) {
      const int ln = dir ? (L_ - 2 - s) : (s + 1);
      gA_n = gxb[(size_t)ln * 2048 + offA];
      gB_n = gxb[(size_t)ln * 2048 + offB];
    }
    float a0 = 0.f, a1 = 0.f, a2 = 0.f, a3 = 0.f;
    #pragma unroll
    for (int q = 0; q < 16; ++q) {
      uint4 hv = h4[buf][ks][q];
      uint4 wv = wo_lds[t * 16 + (q ^ tm)];
      a0 = dot2f(w0[q*4+0], hv.x, a0); a0 = dot2f(w0[q*4+1], hv.y, a0);
      a0 = dot2f(w0[q*4+2], hv.z, a0); a0 = dot2f(w0[q*4+3], hv.w, a0);
      a1 = dot2f(w1[q*4+0], hv.x, a1); a1 = dot2f(w1[q*4+1], hv.y, a1);
      a1 = dot2f(w1[q*4+2], hv.z, a1); a1 = dot2f(w1[q*4+3], hv.w, a1);
      a2 = dot2f(w2[q*4+0], hv.x, a2); a2 = dot2f(w2[q*4+1], hv.y, a2);
      a2 = dot2f(w2[q*4+2], hv.z, a2); a2 = dot2f(w2[q*4+3], hv.w, a2);
      a3 = dot2f(wv.x, hv.x, a3); a3 = dot2f(wv.y, hv.y, a3);
      a3 = dot2f(wv.z, hv.z, a3); a3 = dot2f(wv.w, hv.w, a3);
    }
    if (ks == 0) { a0 += gA; a2 += gB; } else { a1 += gA; a3 += gB; }
    a0 += __shfl_xor(a0, 1, 64);
    a1 += __shfl_xor(a1, 1, 64);
    a2 += __shfl_xor(a2, 1, 64);
    a3 += __shfl_xor(a3, 1, 64);
    const float si = fast_sigmoid(a0);
    const float sf = fast_sigmoid(a1);
    const float tg = fast_tanh(a2);
    const float so = fast_sigmoid(a3);
    c_reg = fmaf(sf, c_reg, si * tg);
    const float hv = so * fast_tanh(c_reg);
    if (ks == 0) outp[(size_t)(b * L_ + l) * H2 + j] = hv;
    const float hv2 = __shfl_xor(hv, 2, 64);   // unit j+1's h (for even j, ks=0)
    buf ^= 1;
    if ((t & 3) == 0)
      ((unsigned*)h4[buf])[t >> 2] = packf16(hv, hv2);
    gA = gA_n; gB = gB_n;
    __syncthreads();
  }
}

extern "C" void kernel_launch(void* const* d_in, const int* in_sizes, int n_in,
                              void* d_out, int out_size, void* d_ws, size_t ws_size,
                              hipStream_t stream)
{
  const float* x    = (const float*)d_in[0];
  const float* wi   = (const float*)d_in[1];
  const float* cw   = (const float*)d_in[2];
  const float* cb   = (const float*)d_in[3];
  const float* xpw  = (const float*)d_in[4];
  const float* dw   = (const float*)d_in[5];
  const float* db   = (const float*)d_in[6];
  const float* Alog = (const float*)d_in[7];
  const float* Dp   = (const float*)d_in[8];
  const float* wo   = (const float*)d_in[9];
  const float* lng  = (const float*)d_in[10];
  const float* lnb  = (const float*)d_in[11];
  const float* wih  = (const float*)d_in[12];
  const float* whh  = (const float*)d_in[13];
  const float* bih  = (const float*)d_in[14];
  const float* bhh  = (const float*)d_in[15];
  const float* fw   = (const float*)d_in[16];
  const float* fb   = (const float*)d_in[17];
  float* out = (float*)d_out;

  float* F    = (float*)d_ws;
  float* xz   = F;                 // 4,194,304 floats (B*L*2048); aliased with gx
  float* gx   = F;                 // LSTM gate precompute, consumed before mamba chain
  float* u    = F + 4194304;       // 2,097,152
  float* xdbl = F + 6291456;       //   262,144 (2048 x 128, padded)
  float* dt   = F + 6553600;       // 2,097,152
  float* ybuf = F + 8650752;       // 2,097,152
  float* mo   = F + 10747904;      // 1,048,576
  float* mbuf = F + 11796480;      // 1,048,576
  float* lf   = F + 12845056;      //   524,288
  float* lb   = F + 13369344;      //   524,288  (end 13,893,632)
  float* xpw_pad = mo;             // 131,072; pad consumed before mo is written

  const int M = B_ * L_;           // 2048
  dim3 blk(256);

  // LSTM input projection for both dirs + both biases in one GEMM (f16 MFMA):
  gemm_mfma<false><<<dim3(2048/128, M/128), blk, 0, stream>>>(
      x, wih, gx, M, 2048, 512, 512, 512, 2048, bih, bhh);
  lstm_rec<<<dim3(8), dim3(512), 0, stream>>>(gx, whh, lf, lb);

  for (int i = 0; i < NL; ++i) {
    const float* min = (i == 0) ? x : mbuf;
    // padded x_proj weights for this layer (writes into mo region, consumed below)
    pad_xpw<<<dim3(512), blk, 0, stream>>>(xpw + (size_t)i*64*1024, xpw_pad);
    // xz = m @ in_proj_w^T  (MFMA)
    gemm_mfma<false><<<dim3(2048/128, M/128), blk, 0, stream>>>(
        min, wi + (size_t)i*2048*512, xz, M, 2048, 512, 512, 512, 2048, nullptr, nullptr);
    // u = silu(causal depthwise conv(xin) + cb)
    conv_silu<<<dim3((M*DIN)/256), blk, 0, stream>>>(
        xz, cw + (size_t)i*DIN*DCV, cb + i*DIN, u);
    // xdbl = u @ xpw_pad^T  (MFMA, N=128 padded, ldc=128)
    gemm_mfma<false><<<dim3(1, M/128), blk, 0, stream>>>(
        u, xpw_pad, xdbl, M, 128, 1024, 1024, 1024, 128, nullptr, nullptr);
    // dt = softplus(dt_in @ dt_proj_w^T + db)  (K=32 -> fp32 path, lda=128)
    gemm_nt<1><<<dim3(1024/64, M/64), blk, 0, stream>>>(
        xdbl, dw + (size_t)i*1024*32, dt, M, 1024, 32, 128, 32, 1024, db + i*1024);
    // selective scan + D skip + gate by silu(z)
    scan_kernel<<<dim3((B_*DIN*DST)/256), blk, 0, stream>>>(
        dt, u, xdbl, xz, Alog + (size_t)i*DIN*DST, Dp + i*DIN, ybuf);
    // mo = y @ out_proj_w^T  (MFMA)
    gemm_mfma<false><<<dim3(512/128, M/128), blk, 0, stream>>>(
        ybuf, wo + (size_t)i*512*1024, mo, M, 512, 1024, 1024, 1024, 512, nullptr, nullptr);
    // m = layernorm(m + mo)
    resid_ln<<<dim3(M), dim3(64), 0, stream>>>(
        min, mo, lng + i*512, lnb + i*512, mbuf);
  }

  // fusion: out = [m | lf | lb] @ fusion_w^T + fb, as 3 K-split MFMA passes
  gemm_mfma<false><<<dim3(512/128, M/128), blk, 0, stream>>>(
      mbuf, fw,       out, M, 512, 512, 512, 1024, 512, fb, nullptr);
  gemm_mfma<true><<<dim3(512/128, M/128), blk, 0, stream>>>(
      lf,   fw + 512, out, M, 512, 256, 256, 1024, 512, nullptr, nullptr);
  gemm_mfma<true><<<dim3(512/128, M/128), blk, 0, stream>>>(
      lb,   fw + 768, out, M, 512, 256, 256, 1024, 512, nullptr, nullptr);
}